// Round 9
// baseline (3108.776 us; speedup 1.0000x reference)
//
#include <hip/hip_runtime.h>
#include <hip/hip_bf16.h>

// LSTM decoder: L=2, B=64, T=512, H=IN=512, gates G=2048 (i,f,g,o).
// Round 12c (r8 fix: gfx950 assembler requires offset: BEFORE cache flags
// -- "off offset:16 sc0 sc1", not "off sc0 sc1 offset:16"):
// TAGGED-DATA exchange -- poll the data, not a counter.
//  - r7 (barrier topology), r8/r9/r10/r11 (L2 mediation) all neutral or
//    worse => the critical path is the SIGNALING chain: store-drain ->
//    atomic -> counter-poll -> load = ~4 coherent RTs per step.
//  - r12: h words packed [hi bf16 | lo bf16] with lo's 2 LSBs = step tag
//    ETAG(t) = ((t+16)>>4)&3. Consumers load their actual MFMA fragments
//    (sc0 sc1) in a poll loop and check tags: detection==transfer, 2 RTs,
//    per-wave granular, no barrier on the data path.
//  - tag-per-frag validity: a frag (8 cells, 32B) lies inside ONE 64B
//    transaction of the producer's single global_store_dword instruction,
//    so word0's tag certifies the whole frag.
//  - ABA-safe: ring depth 16, tag mod 4 => same-slot occupants differ by
//    +1 tag; consumer lag <=3 steps << 64-step wrap. Replay-safe: init
//    zeroes all non-init slots (tag 0 != first expected tag 1).
//  - slot-reuse guards keep the r7 lagged counters (cnt >= 64*(t-15)):
//    15 steps of slack, never on the critical path.
//  - numerics: hi exact; lo's 2 LSBs rounded away (err <= ~2^-15 abs,
//    budget 2^-8). ih single bf16, hh hi+lo W x hi+lo h (rounds 2-5).
//  - all exchange loads/stores sc0 sc1 (r2-r6 proven); no invs anywhere.

#define TT 512

using short8 = __attribute__((ext_vector_type(8))) short;
using f32x4  = __attribute__((ext_vector_type(4))) float;
using u32x4  = __attribute__((ext_vector_type(4))) unsigned;

__device__ __forceinline__ short f2bf(float f) {
  unsigned u = __float_as_uint(f);
  u = (u + 0x7fffu + ((u >> 16) & 1u)) >> 16;  // RNE
  return (short)u;
}
__device__ __forceinline__ float bf2f(short s) {
  return __uint_as_float(((unsigned)(unsigned short)s) << 16);
}
__device__ __forceinline__ float sigf(float x) { return 1.f / (1.f + __expf(-x)); }
__device__ __forceinline__ float tanh_(float x) { return 1.f - 2.f / (__expf(2.f * x) + 1.f); }
__device__ __forceinline__ unsigned ETAG(int t) {
  return ((unsigned)(t + 16) >> 4) & 3u;
}

// 8 frag-pairs: 16 coherent dwordx4 loads (pair i = ptr_i, ptr_i+16B).
// NOTE gfx950 operand order: off [offset:N] sc0 sc1 (offset before flags).
__device__ __forceinline__ void ld16p(u32x4* R,
    const unsigned* p0, const unsigned* p1, const unsigned* p2,
    const unsigned* p3, const unsigned* p4, const unsigned* p5,
    const unsigned* p6, const unsigned* p7) {
  asm volatile(
      "global_load_dwordx4 %0, %16, off sc0 sc1\n\t"
      "global_load_dwordx4 %1, %16, off offset:16 sc0 sc1\n\t"
      "global_load_dwordx4 %2, %17, off sc0 sc1\n\t"
      "global_load_dwordx4 %3, %17, off offset:16 sc0 sc1\n\t"
      "global_load_dwordx4 %4, %18, off sc0 sc1\n\t"
      "global_load_dwordx4 %5, %18, off offset:16 sc0 sc1\n\t"
      "global_load_dwordx4 %6, %19, off sc0 sc1\n\t"
      "global_load_dwordx4 %7, %19, off offset:16 sc0 sc1\n\t"
      "global_load_dwordx4 %8, %20, off sc0 sc1\n\t"
      "global_load_dwordx4 %9, %20, off offset:16 sc0 sc1\n\t"
      "global_load_dwordx4 %10, %21, off sc0 sc1\n\t"
      "global_load_dwordx4 %11, %21, off offset:16 sc0 sc1\n\t"
      "global_load_dwordx4 %12, %22, off sc0 sc1\n\t"
      "global_load_dwordx4 %13, %22, off offset:16 sc0 sc1\n\t"
      "global_load_dwordx4 %14, %23, off sc0 sc1\n\t"
      "global_load_dwordx4 %15, %23, off offset:16 sc0 sc1"
      : "=&v"(R[0]), "=&v"(R[1]), "=&v"(R[2]), "=&v"(R[3]),
        "=&v"(R[4]), "=&v"(R[5]), "=&v"(R[6]), "=&v"(R[7]),
        "=&v"(R[8]), "=&v"(R[9]), "=&v"(R[10]), "=&v"(R[11]),
        "=&v"(R[12]), "=&v"(R[13]), "=&v"(R[14]), "=&v"(R[15])
      : "v"(p0), "v"(p1), "v"(p2), "v"(p3),
        "v"(p4), "v"(p5), "v"(p6), "v"(p7)
      : "memory");
}

// tie a waitcnt to 16 loaded frags so no use precedes it
#define TIE16(A, CNT)                                                       \
  asm volatile(CNT : "+v"(A[0]), "+v"(A[1]), "+v"(A[2]), "+v"(A[3]),        \
                     "+v"(A[4]), "+v"(A[5]), "+v"(A[6]), "+v"(A[7]),        \
                     "+v"(A[8]), "+v"(A[9]), "+v"(A[10]), "+v"(A[11]),      \
                     "+v"(A[12]), "+v"(A[13]), "+v"(A[14]), "+v"(A[15])     \
               ::"memory")

// coherent write-through stores (reach the device coherence point)
__device__ __forceinline__ void stc_dword(unsigned* p, unsigned v) {
  asm volatile("global_store_dword %0, %1, off sc0 sc1"
               :: "v"(p), "v"(v) : "memory");
}
__device__ __forceinline__ void stc_float(float* p, float v) {
  asm volatile("global_store_dword %0, %1, off sc0 sc1"
               :: "v"(p), "v"(v) : "memory");
}

// ---- x fp32 [64][512][512] -> bf16 in first half of each out row ----
__global__ __launch_bounds__(256) void conv_x(const float* __restrict__ x,
                                              short* __restrict__ xo) {
  size_t g = (size_t)blockIdx.x * 256 + threadIdx.x;  // 2,097,152
  size_t i = g * 8;
  float4 v0 = *(const float4*)(x + i);
  float4 v1 = *(const float4*)(x + i + 4);
  short8 r;
  r[0] = f2bf(v0.x); r[1] = f2bf(v0.y); r[2] = f2bf(v0.z); r[3] = f2bf(v0.w);
  r[4] = f2bf(v1.x); r[5] = f2bf(v1.y); r[6] = f2bf(v1.z); r[7] = f2bf(v1.w);
  *(short8*)(xo + (i >> 9) * 1024 + (i & 511)) = r;
}

// ---- W pack: per-block contiguous LDS image (49152 shorts per (l,j8)) ----
__global__ __launch_bounds__(256) void conv_w(const float* __restrict__ Wih,
                                              const float* __restrict__ Whh,
                                              short* __restrict__ wp) {
  int g = blockIdx.x * 256 + threadIdx.x;  // 0..786431
  int l = g / 393216;
  int rem = g % 393216;
  int j8 = rem / 6144;
  int q8 = rem % 6144;
  int s, hl, bt, c, lane;
  if (q8 < 2048) {
    s = 0; hl = 0;
    int seg = q8 >> 6; bt = seg >> 4; c = seg & 15; lane = q8 & 63;
  } else {
    int q = q8 - 2048;
    s = 1;
    int seg = q >> 6; bt = seg >> 5; c = (seg >> 1) & 15; hl = seg & 1;
    lane = q & 63;
  }
  int r = lane & 15;
  int gg = r >> 2, jj = r & 3;
  int R = gg * 512 + j8 * 8 + bt * 4 + jj;
  int k = c * 32 + (lane >> 4) * 8;
  const float* src = (s ? Whh : Wih) + ((size_t)(l * 2048 + R)) * 512 + k;
  short8 o;
#pragma unroll
  for (int e = 0; e < 8; ++e) {
    float v = src[e];
    short hi = f2bf(v);
    o[e] = hl ? f2bf(v - bf2f(hi)) : hi;
  }
  *(short8*)(wp + (size_t)g * 8) = o;
}

// ---- hp init: pack h0 into slots 15 (L0) / 31 (L1), zero all others ----
// hp layout: [32 slots][k8=64][b=64][e=8] u32 = [hi bf16 | lo bf16+tag].
// Zeroed slots carry tag 0; first expected tag everywhere is 1 => no
// false-fresh, and replay (iteration 2+) is reset cleanly.
__global__ __launch_bounds__(256) void init_state(const float* __restrict__ h0,
                                                  unsigned* __restrict__ hp,
                                                  unsigned* __restrict__ bar) {
  unsigned idx = blockIdx.x * 256 + threadIdx.x;  // < 1,048,576
  int slot = idx >> 15;
  unsigned w = idx & 32767u;
  unsigned word = 0u;
  if (slot == 15 || slot == 31) {
    int l = slot >> 4;
    int k8 = w >> 9, b = (w >> 3) & 63, e = w & 7;
    int j = k8 * 8 + e;
    float h = h0[l * 32768 + b * 512 + j];
    short hi = f2bf(h);
    unsigned lo = (unsigned)(unsigned short)f2bf(h - bf2f(hi));
    lo = (lo + 2u) & 0xFFFCu;  // tag 0 == ETAG(-1)
    word = ((unsigned)(unsigned short)hi << 16) | lo;
  }
  hp[idx] = word;
  if (blockIdx.x < 8) bar[blockIdx.x * 256 + threadIdx.x] = 0u;  // cnt0+cnt1
}

// ---- lagged slot-reuse guards (r7 plumbing; never on the critical path) --
__device__ __forceinline__ unsigned csum(unsigned* c) {
  unsigned s = 0;
#pragma unroll
  for (int r = 0; r < 32; ++r)
    s += __hip_atomic_load(&c[r * 32], __ATOMIC_RELAXED,
                           __HIP_MEMORY_SCOPE_AGENT);
  return s;
}
__device__ __forceinline__ void garrive(unsigned* cnt, int tid, int slot) {
  __syncthreads();  // drains this block's coherent stores
  if (tid == 0)
    __hip_atomic_fetch_add(&cnt[slot * 32], 1u, __ATOMIC_RELAXED,
                           __HIP_MEMORY_SCOPE_AGENT);
}
__device__ __forceinline__ void guard1(unsigned* c1, unsigned t1, int tid) {
  if (tid == 0) {
    while (csum(c1) < t1) __builtin_amdgcn_s_sleep(1);
  }
  __syncthreads();
}
__device__ __forceinline__ void guard2(unsigned* c1, unsigned t1,
                                       unsigned* c2, unsigned t2, int tid) {
  if (tid == 0) {
    for (;;) {
      if (csum(c1) >= t1 && csum(c2) >= t2) break;
      __builtin_amdgcn_s_sleep(1);
    }
  }
  __syncthreads();
}

// ---- persistent LSTM ----------------------------------------------------
// grid 128 = [layer(2)][j8(64)]; block 512 = 8 waves (kq = wv&3, ah = wv>>2).
// dyn LDS 132096B: [0,98304) W image; [98304,..) float sG[4][32][66].
// bar u32 layout: [0,1024) cnt0; [1024,2048) cnt1.
__global__ __launch_bounds__(512, 1) void lstm_persist(
    const short* __restrict__ wp, const float* __restrict__ c0,
    const float* __restrict__ bih, const float* __restrict__ bhh,
    unsigned* __restrict__ hp, unsigned* __restrict__ bar,
    float* __restrict__ out) {
  extern __shared__ char smem[];
  short* lw = (short*)smem;             // 49152 shorts
  float* sG = (float*)(smem + 98304);   // [kq][s][b] stride 66

  const int tid = threadIdx.x;
  const int layer = blockIdx.x >> 6;
  const int j8 = blockIdx.x & 63;
  const int bslot = blockIdx.x & 31;    // 2 blocks per padded counter
  unsigned* cnt0 = bar;
  unsigned* cnt1 = bar + 1024;
  const int wv = tid >> 6;
  const int kq = wv & 3;
  const int ah = wv >> 2;
  const int lane = tid & 63;
  const int m = lane & 15;
  const int koq = lane >> 4;
  const int cbase = kq << 2;

  {  // W slice -> LDS (one-time)
    const short* src = wp + (size_t)(layer * 64 + j8) * 49152;
    for (int i = tid; i < 6144; i += 512)
      *(short8*)(lw + i * 8) = *(const short8*)(src + i * 8);
  }

  const int sb = tid >> 3, sj = tid & 7;
  const int j = (j8 << 3) + sj;
  float creg = c0[layer * 32768 + sb * 512 + j];
  float hf = 0.f;
  float bsum[4];
#pragma unroll
  for (int g = 0; g < 4; ++g)
    bsum[g] = bih[layer * 2048 + g * 512 + j] + bhh[layer * 2048 + g * 512 + j];
  __syncthreads();

  const int br0 = ((ah * 2 + 0) << 4) + m;
  const int br1 = ((ah * 2 + 1) << 4) + m;
  const short* xo = (const short*)out;

  f32x4 acc[2][2];

  auto zacc = [&]() {
#pragma unroll
    for (int u = 0; u < 2; ++u)
#pragma unroll
      for (int v = 0; v < 2; ++v) acc[u][v] = f32x4{0.f, 0.f, 0.f, 0.f};
  };

#define PAU(rX, cc, br) \
  ((rX) + ((((cbase + (cc)) << 2) + koq) << 9) + (br) * 8)

  // poll 8 frag-pairs from a slot until all carry the expected tag
  auto pollLoad = [&](u32x4* R, const unsigned* rp, unsigned et) {
    for (;;) {
      ld16p(R, PAU(rp, 0, br0), PAU(rp, 0, br1), PAU(rp, 1, br0),
               PAU(rp, 1, br1), PAU(rp, 2, br0), PAU(rp, 2, br1),
               PAU(rp, 3, br0), PAU(rp, 3, br1));
      TIE16(R, "s_waitcnt vmcnt(0)");
      int ok = 1;
#pragma unroll
      for (int i = 0; i < 8; ++i) ok &= ((R[2 * i][0] & 3u) == et) ? 1 : 0;
      if (__all(ok)) break;
      __builtin_amdgcn_s_sleep(1);
    }
  };

  // layer-0 ih for a given timestep from bf16 x rows (B-frags from LDS)
  auto ih_l0 = [&](int txt) {
#pragma unroll
    for (int cc = 0; cc < 4; ++cc) {
      const int c = cbase + cc;
      const int k = c * 32 + (koq << 3);
      short8 b0 = *(const short8*)(lw + c * 512 + lane * 8);
      short8 b1 = *(const short8*)(lw + (16 + c) * 512 + lane * 8);
#pragma unroll
      for (int it = 0; it < 2; ++it) {
        const int br = it ? br1 : br0;
        short8 a = *(const short8*)(xo + ((size_t)br * TT + txt) * 1024 + k);
        acc[0][it] = __builtin_amdgcn_mfma_f32_16x16x32_bf16(a, b0, acc[0][it], 0, 0, 0);
        acc[1][it] = __builtin_amdgcn_mfma_f32_16x16x32_bf16(a, b1, acc[1][it], 0, 0, 0);
      }
    }
  };

  // layer-1 ih from a tagged h0 slot (hi halves only; validated numerics)
  auto ih_l1 = [&](const unsigned* rp, unsigned et) {
    u32x4 R[16];
    pollLoad(R, rp, et);
#pragma unroll
    for (int cc = 0; cc < 4; ++cc) {
      const int c = cbase + cc;
      short8 b0 = *(const short8*)(lw + c * 512 + lane * 8);
      short8 b1 = *(const short8*)(lw + (16 + c) * 512 + lane * 8);
#pragma unroll
      for (int it = 0; it < 2; ++it) {
        const int i = cc * 2 + it;
        u32x4 a = R[2 * i], b = R[2 * i + 1];
        u32x4 H;
        H[0] = (a[1] & 0xFFFF0000u) | (a[0] >> 16);
        H[1] = (a[3] & 0xFFFF0000u) | (a[2] >> 16);
        H[2] = (b[1] & 0xFFFF0000u) | (b[0] >> 16);
        H[3] = (b[3] & 0xFFFF0000u) | (b[2] >> 16);
        short8 Ax = *(short8*)&H;
        acc[0][it] = __builtin_amdgcn_mfma_f32_16x16x32_bf16(Ax, b0, acc[0][it], 0, 0, 0);
        acc[1][it] = __builtin_amdgcn_mfma_f32_16x16x32_bf16(Ax, b1, acc[1][it], 0, 0, 0);
      }
    }
  };

  // shared per-step body: tag-poll h(t-1), hh (hi+lo), reduce, update, store.
  // acc must already hold ih(t).
  auto stepBody = [&](const unsigned* rp, int slotOut, int t, unsigned etR,
                      unsigned tagW) {
    u32x4 R[16];
    pollLoad(R, rp, etR);
    short8 Ah[8], Al[8];
#pragma unroll
    for (int i = 0; i < 8; ++i) {
      u32x4 a = R[2 * i], b = R[2 * i + 1];
      u32x4 H, L;
      H[0] = (a[1] & 0xFFFF0000u) | (a[0] >> 16);
      H[1] = (a[3] & 0xFFFF0000u) | (a[2] >> 16);
      H[2] = (b[1] & 0xFFFF0000u) | (b[0] >> 16);
      H[3] = (b[3] & 0xFFFF0000u) | (b[2] >> 16);
      L[0] = (a[1] << 16) | (a[0] & 0xFFFFu);
      L[1] = (a[3] << 16) | (a[2] & 0xFFFFu);
      L[2] = (b[1] << 16) | (b[0] & 0xFFFFu);
      L[3] = (b[3] << 16) | (b[2] & 0xFFFFu);
      Ah[i] = *(short8*)&H;
      Al[i] = *(short8*)&L;
    }

    // ---- hh: hi+lo W x hi+lo h (3 MFMA) ----
#pragma unroll
    for (int cc = 0; cc < 4; ++cc) {
      const int c = cbase + cc;
      short8 bh0 = *(const short8*)(lw + 16384 + (c * 2 + 0) * 512 + lane * 8);
      short8 bl0 = *(const short8*)(lw + 16384 + (c * 2 + 1) * 512 + lane * 8);
      short8 bh1 = *(const short8*)(lw + 16384 + ((16 + c) * 2 + 0) * 512 + lane * 8);
      short8 bl1 = *(const short8*)(lw + 16384 + ((16 + c) * 2 + 1) * 512 + lane * 8);
#pragma unroll
      for (int it = 0; it < 2; ++it) {
        short8 a = Ah[cc * 2 + it];
        short8 al = Al[cc * 2 + it];
        acc[0][it] = __builtin_amdgcn_mfma_f32_16x16x32_bf16(a, bh0, acc[0][it], 0, 0, 0);
        acc[0][it] = __builtin_amdgcn_mfma_f32_16x16x32_bf16(a, bl0, acc[0][it], 0, 0, 0);
        acc[0][it] = __builtin_amdgcn_mfma_f32_16x16x32_bf16(al, bh0, acc[0][it], 0, 0, 0);
        acc[1][it] = __builtin_amdgcn_mfma_f32_16x16x32_bf16(a, bh1, acc[1][it], 0, 0, 0);
        acc[1][it] = __builtin_amdgcn_mfma_f32_16x16x32_bf16(a, bl1, acc[1][it], 0, 0, 0);
        acc[1][it] = __builtin_amdgcn_mfma_f32_16x16x32_bf16(al, bh1, acc[1][it], 0, 0, 0);
      }
    }

    // ---- partials -> sG ----
#pragma unroll
    for (int bt = 0; bt < 2; ++bt)
#pragma unroll
      for (int it = 0; it < 2; ++it) {
        const int srow = bt * 16 + m;
        const int col = ((ah * 2 + it) << 4) + (koq << 2);
#pragma unroll
        for (int r = 0; r < 4; ++r)
          sG[(kq * 32 + srow) * 66 + col + r] = acc[bt][it][r];
      }
    __syncthreads();

    // ---- reduce + cell update + tagged pack-store ----
    {
      const int bt = sj >> 2, jl = sj & 3;
      float gv[4];
#pragma unroll
      for (int g = 0; g < 4; ++g) {
        const int s = bt * 16 + g * 4 + jl;
        gv[g] = sG[(0 * 32 + s) * 66 + sb] + sG[(1 * 32 + s) * 66 + sb] +
                sG[(2 * 32 + s) * 66 + sb] + sG[(3 * 32 + s) * 66 + sb] +
                bsum[g];
      }
      const float cn = sigf(gv[1]) * creg + sigf(gv[0]) * tanh_(gv[2]);
      const float hn = sigf(gv[3]) * tanh_(cn);
      creg = cn;
      hf = hn;
      const short hb = f2bf(hn);
      unsigned lo = (unsigned)(unsigned short)f2bf(hn - bf2f(hb));
      lo = ((lo + 2u) & 0xFFFCu) | tagW;
      const unsigned word = ((unsigned)(unsigned short)hb << 16) | lo;
      stc_dword(hp + slotOut * 32768 + (j8 << 9) + tid, word);
      if (layer)
        stc_float(&out[((size_t)sb * 512 + t) * 512 + j], hn);
    }
  };

  if (layer == 0) {
    // -------- layer 0: 16-slot h0 ring, tag-polled --------
    zacc();
    ih_l0(0);  // prologue: ih(t=0) from x
    for (int t = 0; t < TT; ++t) {
      if (t >= 16)
        // lagged slot-reuse guard: self-lap (cnt0) + L1's Ax reads (cnt1)
        guard2(cnt0, 64u * (unsigned)(t - 15), cnt1, 64u * (unsigned)(t - 15),
               tid);
      stepBody(hp + ((t + 15) & 15) * 32768, t & 15, t, ETAG(t - 1), ETAG(t));
      garrive(cnt0, tid, bslot);
      if (t + 1 < TT) {  // overlap next ih with others' steps
        zacc();
        ih_l0(t + 1);
      }
    }
  } else {
    // -------- layer 1: 16-slot h1 ring; ih tag-polls h0 directly --------
    zacc();
    ih_l1(hp + 0 * 32768, ETAG(0));  // h0(0): poll slot 0
    for (int t = 0; t < TT; ++t) {
      if (t >= 16)
        guard1(cnt1, 64u * (unsigned)(t - 15), tid);  // self-lap only
      stepBody(hp + (16 + ((t + 15) & 15)) * 32768, 16 + (t & 15), t,
               ETAG(t - 1), ETAG(t));
      garrive(cnt1, tid, bslot);
      if (t + 1 < TT) {  // shadow: poll h0(t+1) + ih while others finish t
        zacc();
        ih_l1(hp + ((t + 1) & 15) * 32768, ETAG(t + 1));
      }
    }
  }

  // finals from registers
  stc_float(&out[16777216 + layer * 32768 + sb * 512 + j], hf);
  stc_float(&out[16777216 + 65536 + layer * 32768 + sb * 512 + j], creg);
}

// ---- host ---------------------------------------------------------------

extern "C" void kernel_launch(void* const* d_in, const int* in_sizes, int n_in,
                              void* d_out, int out_size, void* d_ws,
                              size_t ws_size, hipStream_t stream) {
  const float* x = (const float*)d_in[0];
  const float* h0 = (const float*)d_in[1];
  const float* c0 = (const float*)d_in[2];
  const float* Wih = (const float*)d_in[3];
  const float* Whh = (const float*)d_in[4];
  const float* bih = (const float*)d_in[5];
  const float* bhh = (const float*)d_in[6];
  float* out = (float*)d_out;

  char* ws = (char*)d_ws;
  short* wp = (short*)(ws + 0);                // 12 MB packed W images
  unsigned* hp = (unsigned*)(ws + 12582912);   // 4 MB [32 slots][k8][b][8] u32
  unsigned* bar = (unsigned*)(ws + 16777216);  // 8 KB: cnt0 + cnt1
  // total ws use: ~16.8 MB

  hipFuncSetAttribute(reinterpret_cast<const void*>(lstm_persist),
                      hipFuncAttributeMaxDynamicSharedMemorySize, 132096);

  conv_x<<<8192, 256, 0, stream>>>(x, (short*)out);
  conv_w<<<3072, 256, 0, stream>>>(Wih, Whh, wp);
  init_state<<<4096, 256, 0, stream>>>(h0, hp, bar);

  void* args[] = {(void*)&wp, (void*)&c0,  (void*)&bih, (void*)&bhh,
                  (void*)&hp, (void*)&bar, (void*)&out};
  (void)hipLaunchCooperativeKernel(reinterpret_cast<void*>(lstm_persist),
                                   dim3(128), dim3(512), args, 132096, stream);
}

// Round 10
// 2741.936 us; speedup vs baseline: 1.1338x; 1.1338x over previous
//
#include <hip/hip_runtime.h>
#include <hip/hip_bf16.h>

// LSTM decoder: L=2, B=64, T=512, H=IN=512, gates G=2048 (i,f,g,o).
// FINAL (revert to proven best): round-6 latency-engineered persistent
// kernel, 2660-2734 us measured. Session post-mortem (rounds 7-12):
//  - barrier topology (r7), L2-mediated exchange w/ per-block, leader, and
//    epoch invalidation (r8/r10/r11), and tagged-data polling (r12) were
//    ALL neutral or negative. Step time ~5.2 us is invariant: it is set by
//    serialized coherent MALL round trips (store-drain, atomic propagate,
//    detect, data load ~0.4 us each) + the synchronized ~2 MB/step h
//    broadcast burst + ~0.6 us compute, times 512 serial steps.
//  - structural escapes are closed: intra-XCD exchange needs j16 tiles
//    (192 KB W > 160 KB LDS); the dense recurrence cannot reduce its
//    serial exchange count.
// Structure:
//  - split-phase fence-free barrier (arrive early / wait late), 32 padded
//    counters, relaxed agent atomics (no L2 flush/inv -- round-5 proven)
//  - ALL coherent h loads issued in one burst; tied s_waitcnt vmcnt(16)
//    starts layer-1 ih while hh operands are still in flight; vmcnt(0)
//    before hh. One MALL round-trip per step instead of three.
//  - layer-0 ih(t+1) computed AFTER arrival (overlaps other blocks' wait);
//    x pre-converted to bf16 into d_out rows (row (b,t) consumed at phase t,
//    overwritten by layer-1 at phase t+1 -- barrier-ordered, round-3 proven).
// Numerics = validated rounds 2-5: ih single bf16, hh hi+lo W x hi+lo h.

#define TT 512

using short8 = __attribute__((ext_vector_type(8))) short;
using f32x4  = __attribute__((ext_vector_type(4))) float;

__device__ __forceinline__ short f2bf(float f) {
  unsigned u = __float_as_uint(f);
  u = (u + 0x7fffu + ((u >> 16) & 1u)) >> 16;  // RNE
  return (short)u;
}
__device__ __forceinline__ float bf2f(short s) {
  return __uint_as_float(((unsigned)(unsigned short)s) << 16);
}
__device__ __forceinline__ float sigf(float x) { return 1.f / (1.f + __expf(-x)); }
__device__ __forceinline__ float tanh_(float x) { return 1.f - 2.f / (__expf(2.f * x) + 1.f); }

// 8 coherent 16B loads, NO wait (caller ties the waitcnt to the results).
__device__ __forceinline__ void ld8_nw(short8* d,
    const short* p0, const short* p1, const short* p2, const short* p3,
    const short* p4, const short* p5, const short* p6, const short* p7) {
  asm volatile(
      "global_load_dwordx4 %0, %8, off sc0 sc1\n\t"
      "global_load_dwordx4 %1, %9, off sc0 sc1\n\t"
      "global_load_dwordx4 %2, %10, off sc0 sc1\n\t"
      "global_load_dwordx4 %3, %11, off sc0 sc1\n\t"
      "global_load_dwordx4 %4, %12, off sc0 sc1\n\t"
      "global_load_dwordx4 %5, %13, off sc0 sc1\n\t"
      "global_load_dwordx4 %6, %14, off sc0 sc1\n\t"
      "global_load_dwordx4 %7, %15, off sc0 sc1"
      : "=&v"(d[0]), "=&v"(d[1]), "=&v"(d[2]), "=&v"(d[3]),
        "=&v"(d[4]), "=&v"(d[5]), "=&v"(d[6]), "=&v"(d[7])
      : "v"(p0), "v"(p1), "v"(p2), "v"(p3),
        "v"(p4), "v"(p5), "v"(p6), "v"(p7)
      : "memory");
}

// tie a waitcnt (or nothing) to 8 loaded fragments so no use precedes it
#define TIE8(A, CNT)                                                        \
  asm volatile(CNT : "+v"(A[0]), "+v"(A[1]), "+v"(A[2]), "+v"(A[3]),        \
                     "+v"(A[4]), "+v"(A[5]), "+v"(A[6]), "+v"(A[7])         \
               ::"memory")

// coherent 2B store (write-through to device coherence point)
__device__ __forceinline__ void stc_short(short* p, short v) {
  asm volatile("global_store_short %0, %1, off sc0 sc1"
               :: "v"(p), "v"((int)v) : "memory");
}

// ---- x fp32 [64][512][512] -> bf16 in first half of each out row ----
__global__ __launch_bounds__(256) void conv_x(const float* __restrict__ x,
                                              short* __restrict__ xo) {
  size_t g = (size_t)blockIdx.x * 256 + threadIdx.x;  // 2,097,152
  size_t i = g * 8;
  float4 v0 = *(const float4*)(x + i);
  float4 v1 = *(const float4*)(x + i + 4);
  short8 r;
  r[0] = f2bf(v0.x); r[1] = f2bf(v0.y); r[2] = f2bf(v0.z); r[3] = f2bf(v0.w);
  r[4] = f2bf(v1.x); r[5] = f2bf(v1.y); r[6] = f2bf(v1.z); r[7] = f2bf(v1.w);
  *(short8*)(xo + (i >> 9) * 1024 + (i & 511)) = r;
}

// ---- W pack: per-block contiguous LDS image (49152 shorts per (l,j8)) ----
__global__ __launch_bounds__(256) void conv_w(const float* __restrict__ Wih,
                                              const float* __restrict__ Whh,
                                              short* __restrict__ wp) {
  int g = blockIdx.x * 256 + threadIdx.x;  // 0..786431
  int l = g / 393216;
  int rem = g % 393216;
  int j8 = rem / 6144;
  int q8 = rem % 6144;
  int s, hl, bt, c, lane;
  if (q8 < 2048) {
    s = 0; hl = 0;
    int seg = q8 >> 6; bt = seg >> 4; c = seg & 15; lane = q8 & 63;
  } else {
    int q = q8 - 2048;
    s = 1;
    int seg = q >> 6; bt = seg >> 5; c = (seg >> 1) & 15; hl = seg & 1;
    lane = q & 63;
  }
  int r = lane & 15;
  int gg = r >> 2, jj = r & 3;
  int R = gg * 512 + j8 * 8 + bt * 4 + jj;
  int k = c * 32 + (lane >> 4) * 8;
  const float* src = (s ? Whh : Wih) + ((size_t)(l * 2048 + R)) * 512 + k;
  short8 o;
#pragma unroll
  for (int e = 0; e < 8; ++e) {
    float v = src[e];
    short hi = f2bf(v);
    o[e] = hl ? f2bf(v - bf2f(hi)) : hi;
  }
  *(short8*)(wp + (size_t)g * 8) = o;
}

// ---- h0 -> parity-0 slots, blocked layout [slot][k8=64][b=64][e=8] ----
__global__ __launch_bounds__(256) void init_state(const float* __restrict__ h0,
                                                  short* __restrict__ hhi,
                                                  short* __restrict__ hlo,
                                                  unsigned* __restrict__ bar) {
  int i = blockIdx.x * 256 + threadIdx.x;  // 0..65535 [l][b][j]
  int l = i >> 15, bj = i & 32767;
  int b = bj >> 9, j = bj & 511;
  float h = h0[i];
  short hi = f2bf(h);
  int o = (l * 2) * 32768 + (j >> 3) * 512 + b * 8 + (j & 7);
  hhi[o] = hi;
  hlo[o] = f2bf(h - bf2f(hi));
  if (blockIdx.x < 4) bar[blockIdx.x * 256 + threadIdx.x] = 0u;
}

// ---- split-phase fence-free grid barrier ----
__device__ __forceinline__ void garrive(unsigned* bar, int tid, int slot) {
  __syncthreads();  // drains coherent h stores (vmcnt(0) before s_barrier)
  if (tid == 0)
    __hip_atomic_fetch_add(&bar[slot * 32], 1u, __ATOMIC_RELAXED,
                           __HIP_MEMORY_SCOPE_AGENT);
}
__device__ __forceinline__ void gwait(unsigned* bar, unsigned target, int tid) {
  if (tid == 0) {
    for (;;) {
      unsigned sum = 0;
#pragma unroll
      for (int r = 0; r < 32; ++r)
        sum += __hip_atomic_load(&bar[r * 32], __ATOMIC_RELAXED,
                                 __HIP_MEMORY_SCOPE_AGENT);
      if (sum >= target) break;
      __builtin_amdgcn_s_sleep(1);
    }
  }
  __syncthreads();
}

// ---- persistent LSTM ----------------------------------------------------
// grid 128 = [layer(2)][j8(64)]; block 512 = 8 waves (kq = wv&3, ah = wv>>2).
// dyn LDS 132096B: [0,98304) W image; [98304,..) float sG[4][32][66].
__global__ __launch_bounds__(512, 1) void lstm_persist(
    const short* __restrict__ wp, const float* __restrict__ c0,
    const float* __restrict__ bih, const float* __restrict__ bhh,
    short* __restrict__ hhi, short* __restrict__ hlo,
    unsigned* __restrict__ bar, float* __restrict__ out) {
  extern __shared__ char smem[];
  short* lw = (short*)smem;             // 49152 shorts
  float* sG = (float*)(smem + 98304);   // [kq][s][b] stride 66

  const int tid = threadIdx.x;
  const int layer = blockIdx.x >> 6;
  const int j8 = blockIdx.x & 63;
  const int bslot = blockIdx.x & 31;
  const int wv = tid >> 6;
  const int kq = wv & 3;
  const int ah = wv >> 2;
  const int lane = tid & 63;
  const int m = lane & 15;
  const int koq = lane >> 4;
  const int cbase = kq << 2;

  {  // W slice -> LDS (one-time)
    const short* src = wp + (size_t)(layer * 64 + j8) * 49152;
    for (int i = tid; i < 6144; i += 512)
      *(short8*)(lw + i * 8) = *(const short8*)(src + i * 8);
  }

  const int sb = tid >> 3, sj = tid & 7;
  const int j = (j8 << 3) + sj;
  float creg = c0[layer * 32768 + sb * 512 + j];
  float hf = 0.f;
  float bsum[4];
#pragma unroll
  for (int g = 0; g < 4; ++g)
    bsum[g] = bih[layer * 2048 + g * 512 + j] + bhh[layer * 2048 + g * 512 + j];
  __syncthreads();

  const int br0 = ((ah * 2 + 0) << 4) + m;
  const int br1 = ((ah * 2 + 1) << 4) + m;
  const short* xo = (const short*)out;

  f32x4 acc[2][2];

  // layer-0 ih for a given timestep from bf16 x rows (B-frags from LDS)
  auto ih_l0 = [&](int txt) {
#pragma unroll
    for (int cc = 0; cc < 4; ++cc) {
      const int c = cbase + cc;
      const int k = c * 32 + (koq << 3);
      short8 b0 = *(const short8*)(lw + c * 512 + lane * 8);
      short8 b1 = *(const short8*)(lw + (16 + c) * 512 + lane * 8);
#pragma unroll
      for (int it = 0; it < 2; ++it) {
        const int br = it ? br1 : br0;
        short8 a = *(const short8*)(xo + ((size_t)br * TT + txt) * 1024 + k);
        acc[0][it] = __builtin_amdgcn_mfma_f32_16x16x32_bf16(a, b0, acc[0][it], 0, 0, 0);
        acc[1][it] = __builtin_amdgcn_mfma_f32_16x16x32_bf16(a, b1, acc[1][it], 0, 0, 0);
      }
    }
  };

  if (layer == 0) {
#pragma unroll
    for (int u = 0; u < 2; ++u)
#pragma unroll
      for (int v = 0; v < 2; ++v) acc[u][v] = f32x4{0.f, 0.f, 0.f, 0.f};
    ih_l0(0);  // prologue: ih(t=0)
  }

#define PA(rX, cc, br) \
  ((rX) + ((((cbase + (cc)) << 2) + koq) << 9) + (br) * 8)

  for (int t = 0; t <= TT; ++t) {
    const int tl = layer ? (t - 1) : t;
    if (tl >= 0 && tl < TT) {
      const int pin = tl & 1, pout = pin ^ 1;
      if (t > 0) gwait(bar, 128u * (unsigned)t, tid);

      short8 Ah[8], Al[8];
      const short* rh = hhi + (layer * 2 + pin) * 32768;
      const short* rl = hlo + (layer * 2 + pin) * 32768;

      if (layer == 0) {
        // acc holds ih(t) (computed post-arrival last phase). One trip for hh.
        ld8_nw(Ah, PA(rh, 0, br0), PA(rh, 0, br1), PA(rh, 1, br0), PA(rh, 1, br1),
                   PA(rh, 2, br0), PA(rh, 2, br1), PA(rh, 3, br0), PA(rh, 3, br1));
        ld8_nw(Al, PA(rl, 0, br0), PA(rl, 0, br1), PA(rl, 1, br0), PA(rl, 1, br1),
                   PA(rl, 2, br0), PA(rl, 2, br1), PA(rl, 3, br0), PA(rl, 3, br1));
        TIE8(Ah, "s_waitcnt vmcnt(0)");
        TIE8(Al, "");
      } else {
#pragma unroll
        for (int u = 0; u < 2; ++u)
#pragma unroll
          for (int v = 0; v < 2; ++v) acc[u][v] = f32x4{0.f, 0.f, 0.f, 0.f};
        short8 Ax[8];
        const short* ph = hhi + (t & 1) * 32768;  // layer0 h(tl)
        ld8_nw(Ax, PA(ph, 0, br0), PA(ph, 0, br1), PA(ph, 1, br0), PA(ph, 1, br1),
                   PA(ph, 2, br0), PA(ph, 2, br1), PA(ph, 3, br0), PA(ph, 3, br1));
        ld8_nw(Ah, PA(rh, 0, br0), PA(rh, 0, br1), PA(rh, 1, br0), PA(rh, 1, br1),
                   PA(rh, 2, br0), PA(rh, 2, br1), PA(rh, 3, br0), PA(rh, 3, br1));
        ld8_nw(Al, PA(rl, 0, br0), PA(rl, 0, br1), PA(rl, 1, br0), PA(rl, 1, br1),
                   PA(rl, 2, br0), PA(rl, 2, br1), PA(rl, 3, br0), PA(rl, 3, br1));
        TIE8(Ax, "s_waitcnt vmcnt(16)");  // Ax (oldest 8) done; Ah/Al in flight
#pragma unroll
        for (int cc = 0; cc < 4; ++cc) {
          const int c = cbase + cc;
          short8 b0 = *(const short8*)(lw + c * 512 + lane * 8);
          short8 b1 = *(const short8*)(lw + (16 + c) * 512 + lane * 8);
#pragma unroll
          for (int it = 0; it < 2; ++it) {
            short8 a = Ax[cc * 2 + it];
            acc[0][it] = __builtin_amdgcn_mfma_f32_16x16x32_bf16(a, b0, acc[0][it], 0, 0, 0);
            acc[1][it] = __builtin_amdgcn_mfma_f32_16x16x32_bf16(a, b1, acc[1][it], 0, 0, 0);
          }
        }
        TIE8(Ah, "s_waitcnt vmcnt(0)");
        TIE8(Al, "");
      }

      // ---- hh: hi+lo W x hi+lo h (3 MFMA) ----
#pragma unroll
      for (int cc = 0; cc < 4; ++cc) {
        const int c = cbase + cc;
        short8 bh0 = *(const short8*)(lw + 16384 + (c * 2 + 0) * 512 + lane * 8);
        short8 bl0 = *(const short8*)(lw + 16384 + (c * 2 + 1) * 512 + lane * 8);
        short8 bh1 = *(const short8*)(lw + 16384 + ((16 + c) * 2 + 0) * 512 + lane * 8);
        short8 bl1 = *(const short8*)(lw + 16384 + ((16 + c) * 2 + 1) * 512 + lane * 8);
#pragma unroll
        for (int it = 0; it < 2; ++it) {
          short8 a = Ah[cc * 2 + it];
          short8 al = Al[cc * 2 + it];
          acc[0][it] = __builtin_amdgcn_mfma_f32_16x16x32_bf16(a, bh0, acc[0][it], 0, 0, 0);
          acc[0][it] = __builtin_amdgcn_mfma_f32_16x16x32_bf16(a, bl0, acc[0][it], 0, 0, 0);
          acc[0][it] = __builtin_amdgcn_mfma_f32_16x16x32_bf16(al, bh0, acc[0][it], 0, 0, 0);
          acc[1][it] = __builtin_amdgcn_mfma_f32_16x16x32_bf16(a, bh1, acc[1][it], 0, 0, 0);
          acc[1][it] = __builtin_amdgcn_mfma_f32_16x16x32_bf16(a, bl1, acc[1][it], 0, 0, 0);
          acc[1][it] = __builtin_amdgcn_mfma_f32_16x16x32_bf16(al, bh1, acc[1][it], 0, 0, 0);
        }
      }

      // ---- partials -> sG ----
#pragma unroll
      for (int bt = 0; bt < 2; ++bt)
#pragma unroll
        for (int it = 0; it < 2; ++it) {
          const int srow = bt * 16 + m;
          const int col = ((ah * 2 + it) << 4) + (koq << 2);
#pragma unroll
          for (int r = 0; r < 4; ++r)
            sG[(kq * 32 + srow) * 66 + col + r] = acc[bt][it][r];
        }
      __syncthreads();

      // ---- reduce + cell update ----
      {
        const int bt = sj >> 2, jl = sj & 3;
        float gv[4];
#pragma unroll
        for (int g = 0; g < 4; ++g) {
          const int s = bt * 16 + g * 4 + jl;
          gv[g] = sG[(0 * 32 + s) * 66 + sb] + sG[(1 * 32 + s) * 66 + sb] +
                  sG[(2 * 32 + s) * 66 + sb] + sG[(3 * 32 + s) * 66 + sb] +
                  bsum[g];
        }
        const float cn = sigf(gv[1]) * creg + sigf(gv[0]) * tanh_(gv[2]);
        const float hn = sigf(gv[3]) * tanh_(cn);
        creg = cn;
        hf = hn;
        const int ho = (layer * 2 + pout) * 32768 + (j8 << 9) + tid;
        const short hb = f2bf(hn);
        stc_short(hhi + ho, hb);
        stc_short(hlo + ho, f2bf(hn - bf2f(hb)));
        if (layer)
          __builtin_nontemporal_store(hn, &out[((size_t)sb * 512 + tl) * 512 + j]);
      }
    }
    if (t < TT) {
      garrive(bar, tid, bslot);
      if (layer == 0 && t + 1 < TT) {  // overlap next ih with others' wait
#pragma unroll
        for (int u = 0; u < 2; ++u)
#pragma unroll
          for (int v = 0; v < 2; ++v) acc[u][v] = f32x4{0.f, 0.f, 0.f, 0.f};
        ih_l0(t + 1);
      }
    }
  }

  // finals from registers
  out[16777216 + layer * 32768 + sb * 512 + j] = hf;
  out[16777216 + 65536 + layer * 32768 + sb * 512 + j] = creg;
}

// ---- host ---------------------------------------------------------------

extern "C" void kernel_launch(void* const* d_in, const int* in_sizes, int n_in,
                              void* d_out, int out_size, void* d_ws,
                              size_t ws_size, hipStream_t stream) {
  const float* x = (const float*)d_in[0];
  const float* h0 = (const float*)d_in[1];
  const float* c0 = (const float*)d_in[2];
  const float* Wih = (const float*)d_in[3];
  const float* Whh = (const float*)d_in[4];
  const float* bih = (const float*)d_in[5];
  const float* bhh = (const float*)d_in[6];
  float* out = (float*)d_out;

  char* ws = (char*)d_ws;
  short* wp = (short*)(ws + 0);            // 12 MB  fragment-packed W images
  short* hhi = (short*)(ws + 12582912);    // 256 KB h hi [4 slots][k8][b][8]
  short* hlo = (short*)(ws + 12845056);    // 256 KB h lo
  unsigned* bar = (unsigned*)(ws + 13107200);  // 4 KB: 32 padded counters
  // total ws use: ~12.6 MB (round-2-proven budget)

  hipFuncSetAttribute(reinterpret_cast<const void*>(lstm_persist),
                      hipFuncAttributeMaxDynamicSharedMemorySize, 132096);

  conv_x<<<8192, 256, 0, stream>>>(x, (short*)out);
  conv_w<<<3072, 256, 0, stream>>>(Wih, Whh, wp);
  init_state<<<256, 256, 0, stream>>>(h0, hhi, hlo, bar);

  void* args[] = {(void*)&wp,  (void*)&c0,  (void*)&bih, (void*)&bhh,
                  (void*)&hhi, (void*)&hlo, (void*)&bar, (void*)&out};
  hipLaunchCooperativeKernel(reinterpret_cast<void*>(lstm_persist), dim3(128),
                             dim3(512), args, 132096, stream);
}